// Round 12
// baseline (504.028 us; speedup 1.0000x reference)
//
#include <hip/hip_runtime.h>
#include <cmath>

#define SS 45
#define FSPLIT 16

typedef __attribute__((ext_vector_type(8))) _Float16 half8;
typedef __attribute__((ext_vector_type(4))) float float4v;

__device__ inline unsigned short f16b(float f) {
    union { _Float16 h; unsigned short u; } c;
    c.h = (_Float16)f;
    return c.u;
}
__device__ inline float f16back(unsigned short u) {
    union { _Float16 h; unsigned short u; } c;
    c.u = u;
    return (float)c.h;
}

__device__ __forceinline__ void async16(const void* g, void* l) {
    __builtin_amdgcn_global_load_lds(
        (const __attribute__((address_space(1))) void*)g,
        (__attribute__((address_space(3))) void*)l, 16, 0, 0);
}

// DPP cross-lane reduce helpers (VALU pipe). 0xB1=xor1, 0x4E=xor2,
// 0x141=row_half_mirror (xor7 within 8), 0x128=row_ror:8 (xor8 within 16).
template <int CTRL>
__device__ __forceinline__ float dppadd(float v) {
    int x = __builtin_amdgcn_mov_dpp(__float_as_int(v), CTRL, 0xF, 0xF, true);
    return v + __int_as_float(x);
}
template <int CTRL>
__device__ __forceinline__ float dppmax(float v) {
    int x = __builtin_amdgcn_mov_dpp(__float_as_int(v), CTRL, 0xF, 0xF, true);
    return fmaxf(v, __int_as_float(x));
}

// ---- fused conversion: x -> xh/xl (fp16 hi + residual), W -> WT hi/lo ---------
__global__ __launch_bounds__(256) void conv_kernel(
    const float4* __restrict__ x4, ushort4* __restrict__ xh4, ushort4* __restrict__ xl4,
    const float* __restrict__ Wq, const float* __restrict__ Wk, const float* __restrict__ Wv,
    unsigned short* __restrict__ WTh, unsigned short* __restrict__ WTl)
{
    int bid = blockIdx.x;
    if (bid < 8192) {
        int i = bid * 256 + threadIdx.x;
        float4 v = x4[i];
        float fv[4] = {v.x, v.y, v.z, v.w};
        ushort4 h, l;
        unsigned short hh[4], ll[4];
        #pragma unroll
        for (int e = 0; e < 4; e++) {
            hh[e] = f16b(fv[e]);
            ll[e] = f16b(fv[e] - f16back(hh[e]));
        }
        h.x = hh[0]; h.y = hh[1]; h.z = hh[2]; h.w = hh[3];
        l.x = ll[0]; l.y = ll[1]; l.z = ll[2]; l.w = ll[3];
        xh4[i] = h; xl4[i] = l;
    } else {
        int wb = bid - 8192;
        int zy = wb >> 8;
        int bxy = wb & 255;
        const float* W = (zy == 0) ? Wq : (zy == 1) ? Wk : Wv;
        unsigned short* th = WTh + (size_t)zy * 262144;
        unsigned short* tl = WTl + (size_t)zy * 262144;
        __shared__ float t[32][33];
        int bx = bxy & 15, by = bxy >> 4;
        int tx = threadIdx.x & 31, ty = threadIdx.x >> 5;
        for (int i = ty; i < 32; i += 8) t[i][tx] = W[(size_t)(by * 32 + i) * 512 + bx * 32 + tx];
        __syncthreads();
        for (int i = ty; i < 32; i += 8) {
            float f = t[tx][i];
            unsigned short h = f16b(f);
            unsigned short lo = f16b(f - f16back(h));
            th[(size_t)(bx * 32 + i) * 512 + by * 32 + tx] = h;
            tl[(size_t)(bx * 32 + i) * 512 + by * 32 + tx] = lo;
        }
    }
}

// ---- fused Q,K,V projection: LDS staging via global_load_lds ------------------
// grid (128,4); block 128m x 128n (4 waves of 64x64). BK=32, 16 k-iters.
// 7 LDS tiles of 128x32 fp16 (Ah, Al, Bqh, Bql, Bkh, Bkl, Bvh) = 56 KB.
// Q,K use 2-plane split-fp16 (hh+hl+lh, selection-exact); V 1-plane.
// XOR chunk swizzle slot = C ^ ((row>>1)&3) -> conflict-free ds_read_b128.
__global__ __launch_bounds__(256, 2) void qkv5_kernel(
    const unsigned short* __restrict__ Xh, const unsigned short* __restrict__ Xl,
    const unsigned short* __restrict__ WTh, const unsigned short* __restrict__ WTl,
    float* __restrict__ Q, float* __restrict__ K, float* __restrict__ V)
{
    __shared__ unsigned short lds[28672];   // 7 * 4096 shorts

    int wave = threadIdx.x >> 6;
    int lane = threadIdx.x & 63;
    int m0blk = blockIdx.x * 128;
    int n0blk = blockIdx.y * 128;
    int fr = lane & 15;
    int C = lane >> 4;

    const unsigned short* gb[7];
    int rb[7];
    gb[0] = Xh;             rb[0] = m0blk;
    gb[1] = Xl;             rb[1] = m0blk;
    gb[2] = WTh;            rb[2] = n0blk;
    gb[3] = WTl;            rb[3] = n0blk;
    gb[4] = WTh + 262144;   rb[4] = n0blk;
    gb[5] = WTl + 262144;   rb[5] = n0blk;
    gb[6] = WTh + 524288;   rb[6] = n0blk;

    int mrb = (wave >> 1) * 64;
    int nrb = (wave & 1) * 64;

    float4v accq[4][4], acck[4][4], accv[4][4];
    #pragma unroll
    for (int i = 0; i < 4; i++)
        #pragma unroll
        for (int j = 0; j < 4; j++) {
            accq[i][j] = (float4v){0.f, 0.f, 0.f, 0.f};
            acck[i][j] = (float4v){0.f, 0.f, 0.f, 0.f};
            accv[i][j] = (float4v){0.f, 0.f, 0.f, 0.f};
        }

    int srow = (lane >> 2);
    int sslot = (lane & 3);

    for (int k0 = 0; k0 < 512; k0 += 32) {
        #pragma unroll
        for (int t = 0; t < 7; t++) {
            #pragma unroll
            for (int inst = 0; inst < 2; inst++) {
                int rloc = wave * 32 + inst * 16 + srow;
                int Cp = sslot ^ ((rloc >> 1) & 3);
                const unsigned short* g = gb[t] + (size_t)(rb[t] + rloc) * 512 + k0 + Cp * 8;
                unsigned short* l = lds + t * 4096 + (wave * 32 + inst * 16) * 32;
                async16(g, l);
            }
        }
        __syncthreads();

        half8 A_h[4], A_l[4];
        #pragma unroll
        for (int i = 0; i < 4; i++) {
            int R = mrb + i * 16 + fr;
            int sl = C ^ ((R >> 1) & 3);
            A_h[i] = *(const half8*)(lds + R * 32 + sl * 8);
            A_l[i] = *(const half8*)(lds + 4096 + R * 32 + sl * 8);
        }
        #pragma unroll
        for (int j = 0; j < 4; j++) {
            int R = nrb + j * 16 + fr;
            int sl = C ^ ((R >> 1) & 3);
            int off = R * 32 + sl * 8;
            half8 Bqh = *(const half8*)(lds + 8192 + off);
            half8 Bql = *(const half8*)(lds + 12288 + off);
            half8 Bkh = *(const half8*)(lds + 16384 + off);
            half8 Bkl = *(const half8*)(lds + 20480 + off);
            half8 Bvh = *(const half8*)(lds + 24576 + off);
            #pragma unroll
            for (int i = 0; i < 4; i++) {
                accq[i][j] = __builtin_amdgcn_mfma_f32_16x16x32_f16(A_h[i], Bqh, accq[i][j], 0, 0, 0);
                accq[i][j] = __builtin_amdgcn_mfma_f32_16x16x32_f16(A_h[i], Bql, accq[i][j], 0, 0, 0);
                accq[i][j] = __builtin_amdgcn_mfma_f32_16x16x32_f16(A_l[i], Bqh, accq[i][j], 0, 0, 0);
                acck[i][j] = __builtin_amdgcn_mfma_f32_16x16x32_f16(A_h[i], Bkh, acck[i][j], 0, 0, 0);
                acck[i][j] = __builtin_amdgcn_mfma_f32_16x16x32_f16(A_h[i], Bkl, acck[i][j], 0, 0, 0);
                acck[i][j] = __builtin_amdgcn_mfma_f32_16x16x32_f16(A_l[i], Bkh, acck[i][j], 0, 0, 0);
                accv[i][j] = __builtin_amdgcn_mfma_f32_16x16x32_f16(A_h[i], Bvh, accv[i][j], 0, 0, 0);
            }
        }
        __syncthreads();
    }

    // C/D layout: col = lane&15, row = (lane>>4)*4 + reg
    int rbase = C * 4, ccol = fr;
    int m0 = m0blk + mrb, n0 = n0blk + nrb;
    #pragma unroll
    for (int i = 0; i < 4; i++)
        #pragma unroll
        for (int j = 0; j < 4; j++) {
            int c = n0 + j * 16 + ccol;
            int h = c >> 6, d = c & 63;
            #pragma unroll
            for (int r = 0; r < 4; r++) {
                int rg = m0 + i * 16 + rbase + r;
                int bb = rg >> 12, l = rg & 4095;
                size_t off = ((size_t)(bb * 8 + h) * 4096 + l) * 64 + d;
                Q[off] = accq[i][j][r];
                K[off] = acck[i][j][r];
                V[off] = accv[i][j][r];
            }
        }
}

// ---------------- M = max_s - mean_s of sampled dots, fp32 ---------------------
// 8 groups of 8 lanes; group g owns s = 8*it+g; lane t covers contiguous 16 B.
// Invalid slots (s>=45) alias sample 0 -> dot == p0; sum45 = sum48 - 3*p0.
__global__ __launch_bounds__(256) void m_kernel(
    const float* __restrict__ Q, const float* __restrict__ K,
    const int* __restrict__ idx, float* __restrict__ M)
{
    int inst = blockIdx.x * 4 + (threadIdx.x >> 6);
    int lane = threadIdx.x & 63;
    int g = lane >> 3;
    int t = lane & 7;
    int bh = inst >> 12;
    int l = inst & 4095;
    float4 qa = *(const float4*)(Q + (size_t)inst * 64 + t * 4);
    float4 qb = *(const float4*)(Q + (size_t)inst * 64 + 32 + t * 4);
    const float* kb = K + (size_t)bh * 4096 * 64;
    const int* irow = idx + (size_t)l * SS;
    int jv[6];
    #pragma unroll
    for (int it = 0; it < 6; it++) {
        int s = it * 8 + g;
        jv[it] = irow[(it == 5 && g >= 5) ? 0 : s];
    }
    float4 kva[6], kvb[6];
    #pragma unroll
    for (int it = 0; it < 6; it++) {
        kva[it] = *(const float4*)(kb + (size_t)jv[it] * 64 + t * 4);
        kvb[it] = *(const float4*)(kb + (size_t)jv[it] * 64 + 32 + t * 4);
    }
    float maxv = -1e30f, sum = 0.f, p0 = 0.f;
    #pragma unroll
    for (int it = 0; it < 6; it++) {
        float p = qa.x * kva[it].x;
        p = fmaf(qa.y, kva[it].y, p);
        p = fmaf(qa.z, kva[it].z, p);
        p = fmaf(qa.w, kva[it].w, p);
        p = fmaf(qb.x, kvb[it].x, p);
        p = fmaf(qb.y, kvb[it].y, p);
        p = fmaf(qb.z, kvb[it].z, p);
        p = fmaf(qb.w, kvb[it].w, p);
        p = dppadd<0xB1>(p);
        p = dppadd<0x4E>(p);
        p = dppadd<0x141>(p);
        if (it == 0) p0 = p;
        maxv = fmaxf(maxv, p);
        sum += p;
    }
    maxv = dppmax<0x128>(maxv);
    maxv = fmaxf(maxv, __shfl_xor(maxv, 16, 64));
    maxv = fmaxf(maxv, __shfl_xor(maxv, 32, 64));
    sum = dppadd<0x128>(sum);
    sum += __shfl_xor(sum, 16, 64);
    sum += __shfl_xor(sum, 32, 64);
    float p0b = __shfl(p0, 0, 64);
    if (lane == 0) M[inst] = maxv - (sum - 3.f * p0b) * (1.f / 45.f);
}

// ---------------- per-(b,h) top-45 of M over L ---------------------------------
__global__ __launch_bounds__(256) void topk_kernel(
    const float* __restrict__ M, int* __restrict__ tidx)
{
    int bh = blockIdx.x;
    __shared__ float vals[4096];
    __shared__ float wv[4];
    __shared__ int wi[4];
    int tid = threadIdx.x;
    int lane = tid & 63, w = tid >> 6;
    for (int i = tid; i < 4096; i += 256) vals[i] = M[(size_t)bh * 4096 + i];
    __syncthreads();
    for (int it = 0; it < SS; it++) {
        float bv = -1e38f; int bi = 0x7fffffff;
        for (int i = tid; i < 4096; i += 256) {
            float v = vals[i];
            if (v > bv) { bv = v; bi = i; }
        }
        #pragma unroll
        for (int s = 32; s > 0; s >>= 1) {
            float v2 = __shfl_xor(bv, s, 64);
            int i2 = __shfl_xor(bi, s, 64);
            if (v2 > bv || (v2 == bv && i2 < bi)) { bv = v2; bi = i2; }
        }
        if (lane == 0) { wv[w] = bv; wi[w] = bi; }
        __syncthreads();
        if (tid == 0) {
            float b0 = wv[0]; int i0 = wi[0];
            #pragma unroll
            for (int k = 1; k < 4; k++)
                if (wv[k] > b0 || (wv[k] == b0 && wi[k] < i0)) { b0 = wv[k]; i0 = wi[k]; }
            tidx[bh * SS + it] = i0;
            vals[i0] = -1e38f;
        }
        __syncthreads();
    }
}

// ---------------- v mean partials over l-chunks --------------------------------
__global__ __launch_bounds__(256) void vmean_part_kernel(
    const float* __restrict__ V, float* __restrict__ vmp)
{
    int bh = blockIdx.x;
    int chunk = blockIdx.y;
    int d = threadIdx.x & 63, part = threadIdx.x >> 6;
    const float* vb = V + ((size_t)bh * 4096 + chunk * 256) * 64;
    float s = 0.f;
    for (int l = part; l < 256; l += 4) s += vb[(size_t)l * 64 + d];
    __shared__ float red[4][64];
    red[part][d] = s;
    __syncthreads();
    if (part == 0) vmp[((size_t)bh * 16 + chunk) * 64 + d] = red[0][d] + red[1][d] + red[2][d] + red[3][d];
}

// ---------------- vmean finalize + base_b = mean_row @ Wo ----------------------
__global__ __launch_bounds__(256) void base_kernel(
    const float* __restrict__ vmp, const float* __restrict__ Wo,
    float* __restrict__ vmean, float* __restrict__ base)
{
    int b = blockIdx.x;
    __shared__ float vmS[512];
    int tid = threadIdx.x;
    for (int i = tid; i < 512; i += 256) {
        int h = i >> 6, d = i & 63;
        float s = 0.f;
        #pragma unroll
        for (int c = 0; c < 16; c++) s += vmp[((size_t)(b * 8 + h) * 16 + c) * 64 + d];
        s *= (1.f / 4096.f);
        vmS[i] = s;
        vmean[(size_t)b * 512 + i] = s;
    }
    __syncthreads();
    for (int j = tid; j < 512; j += 256) {
        float s = 0.f;
        for (int i = 0; i < 512; i++) s += vmS[i] * Wo[(size_t)i * 512 + j];
        base[(size_t)b * 512 + j] = s;
    }
}

// ---------------- flash attention over selected queries ------------------------
__global__ __launch_bounds__(256) void attn_flash_kernel(
    const float* __restrict__ Q, const float* __restrict__ K, const float* __restrict__ V,
    const int* __restrict__ tidx,
    float* __restrict__ Opart, float* __restrict__ mpart, float* __restrict__ lpart)
{
    int split = blockIdx.x;
    int bh = blockIdx.y;
    int L0 = split * (4096 / FSPLIT);

    __shared__ float Qs[48][68];
    __shared__ float Ks[64][68];
    __shared__ float Vs[64][68];
    __shared__ float Ps[48][68];
    __shared__ int tS[48];

    int tid = threadIdx.x;
    int lane = tid & 63, w = tid >> 6;
    if (tid < 48) tS[tid] = (tid < SS) ? tidx[bh * SS + tid] : 0;
    __syncthreads();
    for (int u = w; u < 48; u += 4)
        Qs[u][lane] = Q[((size_t)bh * 4096 + tS[u]) * 64 + lane];

    int ug = tid >> 4, lg = tid & 15;
    float mrun[4], lrun[4], O[4][4];
    #pragma unroll
    for (int i = 0; i < 4; i++) {
        mrun[i] = -1e30f; lrun[i] = 0.f;
        #pragma unroll
        for (int j = 0; j < 4; j++) O[i][j] = 0.f;
    }

    for (int tt = 0; tt < 4096 / FSPLIT / 64; tt++) {
        int lbase = L0 + tt * 64;
        if (tt > 0) __syncthreads();
        for (int r = w; r < 64; r += 4) {
            Ks[r][lane] = K[((size_t)bh * 4096 + lbase + r) * 64 + lane];
            Vs[r][lane] = V[((size_t)bh * 4096 + lbase + r) * 64 + lane];
        }
        __syncthreads();

        if (tid < 192) {
            float acc[4][4];
            #pragma unroll
            for (int i = 0; i < 4; i++)
                #pragma unroll
                for (int j = 0; j < 4; j++) acc[i][j] = 0.f;
            for (int d0 = 0; d0 < 64; d0 += 4) {
                float4 a[4], b[4];
                #pragma unroll
                for (int i = 0; i < 4; i++) a[i] = *(float4*)&Qs[ug * 4 + i][d0];
                #pragma unroll
                for (int j = 0; j < 4; j++) b[j] = *(float4*)&Ks[lg * 4 + j][d0];
                #pragma unroll
                for (int i = 0; i < 4; i++)
                    #pragma unroll
                    for (int j = 0; j < 4; j++)
                        acc[i][j] += a[i].x * b[j].x + a[i].y * b[j].y + a[i].z * b[j].z + a[i].w * b[j].w;
            }
            #pragma unroll
            for (int i = 0; i < 4; i++) {
                #pragma unroll
                for (int j = 0; j < 4; j++) acc[i][j] *= 0.125f;
                float tm = fmaxf(fmaxf(acc[i][0], acc[i][1]), fmaxf(acc[i][2], acc[i][3]));
                tm = fmaxf(tm, __shfl_xor(tm, 1, 64));
                tm = fmaxf(tm, __shfl_xor(tm, 2, 64));
                tm = fmaxf(tm, __shfl_xor(tm, 4, 64));
                tm = fmaxf(tm, __shfl_xor(tm, 8, 64));
                float nm = fmaxf(mrun[i], tm);
                float corr = __expf(mrun[i] - nm);
                float rs = 0.f;
                #pragma unroll
                for (int j = 0; j < 4; j++) {
                    float p = __expf(acc[i][j] - nm);
                    Ps[ug * 4 + i][lg * 4 + j] = p;
                    rs += p;
                }
                rs += __shfl_xor(rs, 1, 64);
                rs += __shfl_xor(rs, 2, 64);
                rs += __shfl_xor(rs, 4, 64);
                rs += __shfl_xor(rs, 8, 64);
                lrun[i] = lrun[i] * corr + rs;
                mrun[i] = nm;
                #pragma unroll
                for (int j = 0; j < 4; j++) O[i][j] *= corr;
            }
        }
        __syncthreads();

        if (tid < 192) {
            for (int l0 = 0; l0 < 64; l0 += 4) {
                float4 vr[4];
                #pragma unroll
                for (int r = 0; r < 4; r++) vr[r] = *(float4*)&Vs[l0 + r][lg * 4];
                #pragma unroll
                for (int i = 0; i < 4; i++) {
                    float4 pv = *(float4*)&Ps[ug * 4 + i][l0];
                    #pragma unroll
                    for (int j = 0; j < 4; j++) {
                        float vj0 = (&vr[0].x)[j], vj1 = (&vr[1].x)[j];
                        float vj2 = (&vr[2].x)[j], vj3 = (&vr[3].x)[j];
                        O[i][j] = fmaf(pv.x, vj0, fmaf(pv.y, vj1, fmaf(pv.z, vj2, fmaf(pv.w, vj3, O[i][j]))));
                    }
                }
            }
        }
    }

    if (tid < 192) {
        #pragma unroll
        for (int i = 0; i < 4; i++) {
            int u = ug * 4 + i;
            if (u < SS) {
                size_t pbase = ((size_t)(bh * FSPLIT + split) * SS + u);
                if (lg == 0) { mpart[pbase] = mrun[i]; lpart[pbase] = lrun[i]; }
                #pragma unroll
                for (int j = 0; j < 4; j++)
                    Opart[pbase * 64 + lg * 4 + j] = O[i][j];
            }
        }
    }
}

// ---------------- combine splits + delta@Wo + scatter into out -----------------
__global__ __launch_bounds__(256) void combine_kernel(
    const float* __restrict__ Opart, const float* __restrict__ mpart, const float* __restrict__ lpart,
    const float* __restrict__ vmean, const float* __restrict__ Wo,
    const int* __restrict__ tidx, float* __restrict__ out)
{
    int rr = blockIdx.x;
    int bh = rr / SS, u = rr % SS;
    int h = bh & 7, b = bh >> 3;
    __shared__ float dS[64];
    int tid = threadIdx.x;
    if (tid < 64) {
        float m = -1e30f;
        #pragma unroll
        for (int s = 0; s < FSPLIT; s++)
            m = fmaxf(m, mpart[(size_t)(bh * FSPLIT + s) * SS + u]);
        float den = 0.f, num = 0.f;
        #pragma unroll
        for (int s = 0; s < FSPLIT; s++) {
            size_t pbase = (size_t)(bh * FSPLIT + s) * SS + u;
            float wgt = __expf(mpart[pbase] - m);
            den += wgt * lpart[pbase];
            num += wgt * Opart[pbase * 64 + tid];
        }
        dS[tid] = num / den - vmean[(size_t)bh * 64 + tid];
    }
    __syncthreads();
    int l = tidx[rr];
    float* orow = out + ((size_t)b * 4096 + l) * 512;
    for (int j = tid; j < 512; j += 256) {
        float s = 0.f;
        #pragma unroll
        for (int dd = 0; dd < 64; dd++) s += dS[dd] * Wo[(size_t)(h * 64 + dd) * 512 + j];
        atomicAdd(orow + j, s);
    }
}

// ---------------- fill out with per-b base row ---------------------------------
__global__ __launch_bounds__(256) void fill_kernel(
    const float4* __restrict__ base4, float4* __restrict__ out4)
{
    int i = blockIdx.x * 256 + threadIdx.x;
    int b = i >> 19;
    int j4 = i & 127;
    out4[i] = base4[b * 128 + j4];
}

extern "C" void kernel_launch(void* const* d_in, const int* in_sizes, int n_in,
                              void* d_out, int out_size, void* d_ws, size_t ws_size,
                              hipStream_t stream)
{
    const float* x  = (const float*)d_in[0];
    const float* Wq = (const float*)d_in[1];
    const float* Wk = (const float*)d_in[2];
    const float* Wv = (const float*)d_in[3];
    const float* Wo = (const float*)d_in[4];
    const int*  idx = (const int*)d_in[5];
    float* out = (float*)d_out;

    float* W = (float*)d_ws;
    float* Q = W;                        // 8,388,608 f
    float* K = W + 8388608;              // 8,388,608 f
    float* V = W + 16777216;             // 8,388,608 f
    unsigned short* xh  = (unsigned short*)(W + 25165824);
    unsigned short* xl  = (unsigned short*)(W + 29360128);
    unsigned short* WTh = (unsigned short*)(W + 33554432);
    unsigned short* WTl = (unsigned short*)(W + 33947648);  // ends 34340864 f = 137.4 MB

    float* Mv    = W + 25165824;         // 131,072
    float* Opart = W + 25296896;         // 1,474,560
    float* mpart = W + 26771456;         // 23,040
    float* lpart = W + 26794496;         // 23,040
    float* vmp   = W + 33406976;         // 32,768
    float* vmean = W + 33439744;         // 2,048
    float* base  = W + 33441792;         // 2,048
    int*   tidx  = (int*)(W + 33443840); // 1,440 ints

    conv_kernel<<<8960, 256, 0, stream>>>((const float4*)x, (ushort4*)xh, (ushort4*)xl,
                                          Wq, Wk, Wv, WTh, WTl);
    qkv5_kernel<<<dim3(128, 4), 256, 0, stream>>>(xh, xl, WTh, WTl, Q, K, V);
    m_kernel<<<32768, 256, 0, stream>>>(Q, K, idx, Mv);
    topk_kernel<<<32, 256, 0, stream>>>(Mv, tidx);
    vmean_part_kernel<<<dim3(32, 16), 256, 0, stream>>>(V, vmp);
    base_kernel<<<4, 256, 0, stream>>>(vmp, Wo, vmean, base);
    fill_kernel<<<8192, 256, 0, stream>>>((const float4*)base, (float4*)out);
    attn_flash_kernel<<<dim3(FSPLIT, 32), 256, 0, stream>>>(Q, K, V, tidx, Opart, mpart, lpart);
    combine_kernel<<<1440, 256, 0, stream>>>(Opart, mpart, lpart, vmean, Wo, tidx, out);
}

// Round 13
// 487.305 us; speedup vs baseline: 1.0343x; 1.0343x over previous
//
#include <hip/hip_runtime.h>
#include <cmath>

#define SS 45
#define FSPLIT 16

typedef __attribute__((ext_vector_type(8))) _Float16 half8;
typedef __attribute__((ext_vector_type(4))) float float4v;

__device__ inline unsigned short f16b(float f) {
    union { _Float16 h; unsigned short u; } c;
    c.h = (_Float16)f;
    return c.u;
}
__device__ inline float f16back(unsigned short u) {
    union { _Float16 h; unsigned short u; } c;
    c.u = u;
    return (float)c.h;
}

__device__ __forceinline__ void async16(const void* g, void* l) {
    __builtin_amdgcn_global_load_lds(
        (const __attribute__((address_space(1))) void*)g,
        (__attribute__((address_space(3))) void*)l, 16, 0, 0);
}

// DPP cross-lane reduce helpers (VALU pipe). 0xB1=xor1, 0x4E=xor2,
// 0x141=row_half_mirror (xor7 within 8), 0x128=row_ror:8 (xor8 within 16).
template <int CTRL>
__device__ __forceinline__ float dppadd(float v) {
    int x = __builtin_amdgcn_mov_dpp(__float_as_int(v), CTRL, 0xF, 0xF, true);
    return v + __int_as_float(x);
}
template <int CTRL>
__device__ __forceinline__ float dppmax(float v) {
    int x = __builtin_amdgcn_mov_dpp(__float_as_int(v), CTRL, 0xF, 0xF, true);
    return fmaxf(v, __int_as_float(x));
}

// ---- fused conversion: x -> xh/xl, W -> WT hi/lo, + vmp zero ------------------
__global__ __launch_bounds__(256) void conv_kernel(
    const float4* __restrict__ x4, ushort4* __restrict__ xh4, ushort4* __restrict__ xl4,
    const float* __restrict__ Wq, const float* __restrict__ Wk, const float* __restrict__ Wv,
    unsigned short* __restrict__ WTh, unsigned short* __restrict__ WTl,
    float* __restrict__ vmp)
{
    int bid = blockIdx.x;
    if (bid < 8192) {
        int i = bid * 256 + threadIdx.x;
        float4 v = x4[i];
        float fv[4] = {v.x, v.y, v.z, v.w};
        ushort4 h, l;
        unsigned short hh[4], ll[4];
        #pragma unroll
        for (int e = 0; e < 4; e++) {
            hh[e] = f16b(fv[e]);
            ll[e] = f16b(fv[e] - f16back(hh[e]));
        }
        h.x = hh[0]; h.y = hh[1]; h.z = hh[2]; h.w = hh[3];
        l.x = ll[0]; l.y = ll[1]; l.z = ll[2]; l.w = ll[3];
        xh4[i] = h; xl4[i] = l;
    } else if (bid < 8960) {
        int wb = bid - 8192;
        int zy = wb >> 8;
        int bxy = wb & 255;
        const float* W = (zy == 0) ? Wq : (zy == 1) ? Wk : Wv;
        unsigned short* th = WTh + (size_t)zy * 262144;
        unsigned short* tl = WTl + (size_t)zy * 262144;
        __shared__ float t[32][33];
        int bx = bxy & 15, by = bxy >> 4;
        int tx = threadIdx.x & 31, ty = threadIdx.x >> 5;
        for (int i = ty; i < 32; i += 8) t[i][tx] = W[(size_t)(by * 32 + i) * 512 + bx * 32 + tx];
        __syncthreads();
        for (int i = ty; i < 32; i += 8) {
            float f = t[tx][i];
            unsigned short h = f16b(f);
            unsigned short lo = f16b(f - f16back(h));
            th[(size_t)(bx * 32 + i) * 512 + by * 32 + tx] = h;
            tl[(size_t)(bx * 32 + i) * 512 + by * 32 + tx] = lo;
        }
    } else {
        for (int i = threadIdx.x; i < 2048; i += 256) vmp[i] = 0.f;
    }
}

// ---- fused Q,K,V projection + vmean partial, LDS staging ----------------------
// grid (128,4); block 128m x 128n (4 waves of 64x64). BK=32, 16 k-iters.
// 7 LDS tiles of 128x32 fp16 = 56 KB. Q,K: 2-plane split-fp16; V: 1-plane.
// Epilogue: per row, the 4 x 64B j-chunks are ADJACENT stores per array ->
// L2 write-combining produces full 256B lines (R12 had 1.73x write amp).
__global__ __launch_bounds__(256, 2) void qkv5_kernel(
    const unsigned short* __restrict__ Xh, const unsigned short* __restrict__ Xl,
    const unsigned short* __restrict__ WTh, const unsigned short* __restrict__ WTl,
    float* __restrict__ Q, float* __restrict__ K, float* __restrict__ V,
    float* __restrict__ vmp)
{
    __shared__ unsigned short lds[28672];   // 7 * 4096 shorts

    int wave = threadIdx.x >> 6;
    int lane = threadIdx.x & 63;
    int m0blk = blockIdx.x * 128;
    int n0blk = blockIdx.y * 128;
    int fr = lane & 15;
    int C = lane >> 4;

    const unsigned short* gb[7];
    int rb[7];
    gb[0] = Xh;             rb[0] = m0blk;
    gb[1] = Xl;             rb[1] = m0blk;
    gb[2] = WTh;            rb[2] = n0blk;
    gb[3] = WTl;            rb[3] = n0blk;
    gb[4] = WTh + 262144;   rb[4] = n0blk;
    gb[5] = WTl + 262144;   rb[5] = n0blk;
    gb[6] = WTh + 524288;   rb[6] = n0blk;

    int mrb = (wave >> 1) * 64;
    int nrb = (wave & 1) * 64;

    float4v accq[4][4], acck[4][4], accv[4][4];
    #pragma unroll
    for (int i = 0; i < 4; i++)
        #pragma unroll
        for (int j = 0; j < 4; j++) {
            accq[i][j] = (float4v){0.f, 0.f, 0.f, 0.f};
            acck[i][j] = (float4v){0.f, 0.f, 0.f, 0.f};
            accv[i][j] = (float4v){0.f, 0.f, 0.f, 0.f};
        }

    int srow = (lane >> 2);
    int sslot = (lane & 3);

    for (int k0 = 0; k0 < 512; k0 += 32) {
        #pragma unroll
        for (int t = 0; t < 7; t++) {
            #pragma unroll
            for (int inst = 0; inst < 2; inst++) {
                int rloc = wave * 32 + inst * 16 + srow;
                int Cp = sslot ^ ((rloc >> 1) & 3);
                const unsigned short* g = gb[t] + (size_t)(rb[t] + rloc) * 512 + k0 + Cp * 8;
                unsigned short* l = lds + t * 4096 + (wave * 32 + inst * 16) * 32;
                async16(g, l);
            }
        }
        __syncthreads();

        half8 A_h[4], A_l[4];
        #pragma unroll
        for (int i = 0; i < 4; i++) {
            int R = mrb + i * 16 + fr;
            int sl = C ^ ((R >> 1) & 3);
            A_h[i] = *(const half8*)(lds + R * 32 + sl * 8);
            A_l[i] = *(const half8*)(lds + 4096 + R * 32 + sl * 8);
        }
        #pragma unroll
        for (int j = 0; j < 4; j++) {
            int R = nrb + j * 16 + fr;
            int sl = C ^ ((R >> 1) & 3);
            int off = R * 32 + sl * 8;
            half8 Bqh = *(const half8*)(lds + 8192 + off);
            half8 Bql = *(const half8*)(lds + 12288 + off);
            half8 Bkh = *(const half8*)(lds + 16384 + off);
            half8 Bkl = *(const half8*)(lds + 20480 + off);
            half8 Bvh = *(const half8*)(lds + 24576 + off);
            #pragma unroll
            for (int i = 0; i < 4; i++) {
                accq[i][j] = __builtin_amdgcn_mfma_f32_16x16x32_f16(A_h[i], Bqh, accq[i][j], 0, 0, 0);
                accq[i][j] = __builtin_amdgcn_mfma_f32_16x16x32_f16(A_h[i], Bql, accq[i][j], 0, 0, 0);
                accq[i][j] = __builtin_amdgcn_mfma_f32_16x16x32_f16(A_l[i], Bqh, accq[i][j], 0, 0, 0);
                acck[i][j] = __builtin_amdgcn_mfma_f32_16x16x32_f16(A_h[i], Bkh, acck[i][j], 0, 0, 0);
                acck[i][j] = __builtin_amdgcn_mfma_f32_16x16x32_f16(A_h[i], Bkl, acck[i][j], 0, 0, 0);
                acck[i][j] = __builtin_amdgcn_mfma_f32_16x16x32_f16(A_l[i], Bkh, acck[i][j], 0, 0, 0);
                accv[i][j] = __builtin_amdgcn_mfma_f32_16x16x32_f16(A_h[i], Bvh, accv[i][j], 0, 0, 0);
            }
        }
        __syncthreads();
    }

    // ---- vmean partial: sum accv over (i,r), then over C-groups (rows) --------
    int hh = n0blk + nrb;            // col base; one head per wave
    int hd = hh >> 6;                // head index
    int bb0 = (m0blk + mrb) >> 12;   // batch (64-row wave tile never crosses)
    {
        float cs[4];
        #pragma unroll
        for (int j = 0; j < 4; j++) {
            float s = 0.f;
            #pragma unroll
            for (int i = 0; i < 4; i++)
                #pragma unroll
                for (int r = 0; r < 4; r++) s += accv[i][j][r];
            s += __shfl_xor(s, 16, 64);
            s += __shfl_xor(s, 32, 64);
            cs[j] = s;
        }
        if (C == 0) {
            #pragma unroll
            for (int j = 0; j < 4; j++)
                atomicAdd(vmp + ((size_t)(bb0 * 8 + hd) * 64) + j * 16 + fr, cs[j]);
        }
    }

    // ---- epilogue: C/D layout col=lane&15, row=(lane>>4)*4+reg ----------------
    int rbase = C * 4;
    int m0 = m0blk + mrb;
    #pragma unroll
    for (int i = 0; i < 4; i++)
        #pragma unroll
        for (int r = 0; r < 4; r++) {
            int rg = m0 + i * 16 + rbase + r;
            int bb = rg >> 12, l = rg & 4095;
            size_t rowoff = ((size_t)(bb * 8 + hd) * 4096 + l) * 64;
            #pragma unroll
            for (int j = 0; j < 4; j++) Q[rowoff + j * 16 + fr] = accq[i][j][r];
            #pragma unroll
            for (int j = 0; j < 4; j++) K[rowoff + j * 16 + fr] = acck[i][j][r];
            #pragma unroll
            for (int j = 0; j < 4; j++) V[rowoff + j * 16 + fr] = accv[i][j][r];
        }
}

// ---------------- M = max_s - mean_s of sampled dots, fp32 ---------------------
__global__ __launch_bounds__(256) void m_kernel(
    const float* __restrict__ Q, const float* __restrict__ K,
    const int* __restrict__ idx, float* __restrict__ M)
{
    int inst = blockIdx.x * 4 + (threadIdx.x >> 6);
    int lane = threadIdx.x & 63;
    int g = lane >> 3;
    int t = lane & 7;
    int bh = inst >> 12;
    int l = inst & 4095;
    float4 qa = *(const float4*)(Q + (size_t)inst * 64 + t * 4);
    float4 qb = *(const float4*)(Q + (size_t)inst * 64 + 32 + t * 4);
    const float* kb = K + (size_t)bh * 4096 * 64;
    const int* irow = idx + (size_t)l * SS;
    int jv[6];
    #pragma unroll
    for (int it = 0; it < 6; it++) {
        int s = it * 8 + g;
        jv[it] = irow[(it == 5 && g >= 5) ? 0 : s];
    }
    float4 kva[6], kvb[6];
    #pragma unroll
    for (int it = 0; it < 6; it++) {
        kva[it] = *(const float4*)(kb + (size_t)jv[it] * 64 + t * 4);
        kvb[it] = *(const float4*)(kb + (size_t)jv[it] * 64 + 32 + t * 4);
    }
    float maxv = -1e30f, sum = 0.f, p0 = 0.f;
    #pragma unroll
    for (int it = 0; it < 6; it++) {
        float p = qa.x * kva[it].x;
        p = fmaf(qa.y, kva[it].y, p);
        p = fmaf(qa.z, kva[it].z, p);
        p = fmaf(qa.w, kva[it].w, p);
        p = fmaf(qb.x, kvb[it].x, p);
        p = fmaf(qb.y, kvb[it].y, p);
        p = fmaf(qb.z, kvb[it].z, p);
        p = fmaf(qb.w, kvb[it].w, p);
        p = dppadd<0xB1>(p);
        p = dppadd<0x4E>(p);
        p = dppadd<0x141>(p);
        if (it == 0) p0 = p;
        maxv = fmaxf(maxv, p);
        sum += p;
    }
    maxv = dppmax<0x128>(maxv);
    maxv = fmaxf(maxv, __shfl_xor(maxv, 16, 64));
    maxv = fmaxf(maxv, __shfl_xor(maxv, 32, 64));
    sum = dppadd<0x128>(sum);
    sum += __shfl_xor(sum, 16, 64);
    sum += __shfl_xor(sum, 32, 64);
    float p0b = __shfl(p0, 0, 64);
    if (lane == 0) M[inst] = maxv - (sum - 3.f * p0b) * (1.f / 45.f);
}

// ---------------- per-(b,h) top-45 of M over L ---------------------------------
__global__ __launch_bounds__(256) void topk_kernel(
    const float* __restrict__ M, int* __restrict__ tidx)
{
    int bh = blockIdx.x;
    __shared__ float vals[4096];
    __shared__ float wv[4];
    __shared__ int wi[4];
    int tid = threadIdx.x;
    int lane = tid & 63, w = tid >> 6;
    for (int i = tid; i < 4096; i += 256) vals[i] = M[(size_t)bh * 4096 + i];
    __syncthreads();
    for (int it = 0; it < SS; it++) {
        float bv = -1e38f; int bi = 0x7fffffff;
        for (int i = tid; i < 4096; i += 256) {
            float v = vals[i];
            if (v > bv) { bv = v; bi = i; }
        }
        #pragma unroll
        for (int s = 32; s > 0; s >>= 1) {
            float v2 = __shfl_xor(bv, s, 64);
            int i2 = __shfl_xor(bi, s, 64);
            if (v2 > bv || (v2 == bv && i2 < bi)) { bv = v2; bi = i2; }
        }
        if (lane == 0) { wv[w] = bv; wi[w] = bi; }
        __syncthreads();
        if (tid == 0) {
            float b0 = wv[0]; int i0 = wi[0];
            #pragma unroll
            for (int k = 1; k < 4; k++)
                if (wv[k] > b0 || (wv[k] == b0 && wi[k] < i0)) { b0 = wv[k]; i0 = wi[k]; }
            tidx[bh * SS + it] = i0;
            vals[i0] = -1e38f;
        }
        __syncthreads();
    }
}

// ---------------- vmean finalize + base_b = mean_row @ Wo ----------------------
__global__ __launch_bounds__(256) void base_kernel(
    const float* __restrict__ vmp, const float* __restrict__ Wo,
    float* __restrict__ vmean, float* __restrict__ base)
{
    int b = blockIdx.x;
    __shared__ float vmS[512];
    int tid = threadIdx.x;
    for (int i = tid; i < 512; i += 256) {
        float s = vmp[(size_t)b * 512 + i] * (1.f / 4096.f);
        vmS[i] = s;
        vmean[(size_t)b * 512 + i] = s;
    }
    __syncthreads();
    for (int j = tid; j < 512; j += 256) {
        float s = 0.f;
        for (int i = 0; i < 512; i++) s += vmS[i] * Wo[(size_t)i * 512 + j];
        base[(size_t)b * 512 + j] = s;
    }
}

// ---------------- flash attention over selected queries ------------------------
__global__ __launch_bounds__(256) void attn_flash_kernel(
    const float* __restrict__ Q, const float* __restrict__ K, const float* __restrict__ V,
    const int* __restrict__ tidx,
    float* __restrict__ Opart, float* __restrict__ mpart, float* __restrict__ lpart)
{
    int split = blockIdx.x;
    int bh = blockIdx.y;
    int L0 = split * (4096 / FSPLIT);

    __shared__ float Qs[48][68];
    __shared__ float Ks[64][68];
    __shared__ float Vs[64][68];
    __shared__ float Ps[48][68];
    __shared__ int tS[48];

    int tid = threadIdx.x;
    int lane = tid & 63, w = tid >> 6;
    if (tid < 48) tS[tid] = (tid < SS) ? tidx[bh * SS + tid] : 0;
    __syncthreads();
    for (int u = w; u < 48; u += 4)
        Qs[u][lane] = Q[((size_t)bh * 4096 + tS[u]) * 64 + lane];

    int ug = tid >> 4, lg = tid & 15;
    float mrun[4], lrun[4], O[4][4];
    #pragma unroll
    for (int i = 0; i < 4; i++) {
        mrun[i] = -1e30f; lrun[i] = 0.f;
        #pragma unroll
        for (int j = 0; j < 4; j++) O[i][j] = 0.f;
    }

    for (int tt = 0; tt < 4096 / FSPLIT / 64; tt++) {
        int lbase = L0 + tt * 64;
        if (tt > 0) __syncthreads();
        for (int r = w; r < 64; r += 4) {
            Ks[r][lane] = K[((size_t)bh * 4096 + lbase + r) * 64 + lane];
            Vs[r][lane] = V[((size_t)bh * 4096 + lbase + r) * 64 + lane];
        }
        __syncthreads();

        if (tid < 192) {
            float acc[4][4];
            #pragma unroll
            for (int i = 0; i < 4; i++)
                #pragma unroll
                for (int j = 0; j < 4; j++) acc[i][j] = 0.f;
            for (int d0 = 0; d0 < 64; d0 += 4) {
                float4 a[4], b[4];
                #pragma unroll
                for (int i = 0; i < 4; i++) a[i] = *(float4*)&Qs[ug * 4 + i][d0];
                #pragma unroll
                for (int j = 0; j < 4; j++) b[j] = *(float4*)&Ks[lg * 4 + j][d0];
                #pragma unroll
                for (int i = 0; i < 4; i++)
                    #pragma unroll
                    for (int j = 0; j < 4; j++)
                        acc[i][j] += a[i].x * b[j].x + a[i].y * b[j].y + a[i].z * b[j].z + a[i].w * b[j].w;
            }
            #pragma unroll
            for (int i = 0; i < 4; i++) {
                #pragma unroll
                for (int j = 0; j < 4; j++) acc[i][j] *= 0.125f;
                float tm = fmaxf(fmaxf(acc[i][0], acc[i][1]), fmaxf(acc[i][2], acc[i][3]));
                tm = fmaxf(tm, __shfl_xor(tm, 1, 64));
                tm = fmaxf(tm, __shfl_xor(tm, 2, 64));
                tm = fmaxf(tm, __shfl_xor(tm, 4, 64));
                tm = fmaxf(tm, __shfl_xor(tm, 8, 64));
                float nm = fmaxf(mrun[i], tm);
                float corr = __expf(mrun[i] - nm);
                float rs = 0.f;
                #pragma unroll
                for (int j = 0; j < 4; j++) {
                    float p = __expf(acc[i][j] - nm);
                    Ps[ug * 4 + i][lg * 4 + j] = p;
                    rs += p;
                }
                rs += __shfl_xor(rs, 1, 64);
                rs += __shfl_xor(rs, 2, 64);
                rs += __shfl_xor(rs, 4, 64);
                rs += __shfl_xor(rs, 8, 64);
                lrun[i] = lrun[i] * corr + rs;
                mrun[i] = nm;
                #pragma unroll
                for (int j = 0; j < 4; j++) O[i][j] *= corr;
            }
        }
        __syncthreads();

        if (tid < 192) {
            for (int l0 = 0; l0 < 64; l0 += 4) {
                float4 vr[4];
                #pragma unroll
                for (int r = 0; r < 4; r++) vr[r] = *(float4*)&Vs[l0 + r][lg * 4];
                #pragma unroll
                for (int i = 0; i < 4; i++) {
                    float4 pv = *(float4*)&Ps[ug * 4 + i][l0];
                    #pragma unroll
                    for (int j = 0; j < 4; j++) {
                        float vj0 = (&vr[0].x)[j], vj1 = (&vr[1].x)[j];
                        float vj2 = (&vr[2].x)[j], vj3 = (&vr[3].x)[j];
                        O[i][j] = fmaf(pv.x, vj0, fmaf(pv.y, vj1, fmaf(pv.z, vj2, fmaf(pv.w, vj3, O[i][j]))));
                    }
                }
            }
        }
    }

    if (tid < 192) {
        #pragma unroll
        for (int i = 0; i < 4; i++) {
            int u = ug * 4 + i;
            if (u < SS) {
                size_t pbase = ((size_t)(bh * FSPLIT + split) * SS + u);
                if (lg == 0) { mpart[pbase] = mrun[i]; lpart[pbase] = lrun[i]; }
                #pragma unroll
                for (int j = 0; j < 4; j++)
                    Opart[pbase * 64 + lg * 4 + j] = O[i][j];
            }
        }
    }
}

// ---------------- combine splits + delta@Wo + scatter into out -----------------
__global__ __launch_bounds__(256) void combine_kernel(
    const float* __restrict__ Opart, const float* __restrict__ mpart, const float* __restrict__ lpart,
    const float* __restrict__ vmean, const float* __restrict__ Wo,
    const int* __restrict__ tidx, float* __restrict__ out)
{
    int rr = blockIdx.x;
    int bh = rr / SS, u = rr % SS;
    int h = bh & 7, b = bh >> 3;
    __shared__ float dS[64];
    int tid = threadIdx.x;
    if (tid < 64) {
        float m = -1e30f;
        #pragma unroll
        for (int s = 0; s < FSPLIT; s++)
            m = fmaxf(m, mpart[(size_t)(bh * FSPLIT + s) * SS + u]);
        float den = 0.f, num = 0.f;
        #pragma unroll
        for (int s = 0; s < FSPLIT; s++) {
            size_t pbase = (size_t)(bh * FSPLIT + s) * SS + u;
            float wgt = __expf(mpart[pbase] - m);
            den += wgt * lpart[pbase];
            num += wgt * Opart[pbase * 64 + tid];
        }
        dS[tid] = num / den - vmean[(size_t)bh * 64 + tid];
    }
    __syncthreads();
    int l = tidx[rr];
    float* orow = out + ((size_t)b * 4096 + l) * 512;
    for (int j = tid; j < 512; j += 256) {
        float s = 0.f;
        #pragma unroll
        for (int dd = 0; dd < 64; dd++) s += dS[dd] * Wo[(size_t)(h * 64 + dd) * 512 + j];
        atomicAdd(orow + j, s);
    }
}

// ---------------- fill out with per-b base row ---------------------------------
__global__ __launch_bounds__(256) void fill_kernel(
    const float4* __restrict__ base4, float4* __restrict__ out4)
{
    int i = blockIdx.x * 256 + threadIdx.x;
    int b = i >> 19;
    int j4 = i & 127;
    out4[i] = base4[b * 128 + j4];
}

extern "C" void kernel_launch(void* const* d_in, const int* in_sizes, int n_in,
                              void* d_out, int out_size, void* d_ws, size_t ws_size,
                              hipStream_t stream)
{
    const float* x  = (const float*)d_in[0];
    const float* Wq = (const float*)d_in[1];
    const float* Wk = (const float*)d_in[2];
    const float* Wv = (const float*)d_in[3];
    const float* Wo = (const float*)d_in[4];
    const int*  idx = (const int*)d_in[5];
    float* out = (float*)d_out;

    float* W = (float*)d_ws;
    float* Q = W;                        // 8,388,608 f
    float* K = W + 8388608;              // 8,388,608 f
    float* V = W + 16777216;             // 8,388,608 f
    unsigned short* xh  = (unsigned short*)(W + 25165824);
    unsigned short* xl  = (unsigned short*)(W + 29360128);
    unsigned short* WTh = (unsigned short*)(W + 33554432);
    unsigned short* WTl = (unsigned short*)(W + 33947648);  // ends 34340864 f
    float* vmp = W + 34340864;           // 2,048 f (live DURING qkv5 -> own space)
    // total 34,342,912 f = 137.4 MB

    float* Mv    = W + 25165824;         // 131,072 (aliases xh, post-qkv5)
    float* Opart = W + 25296896;         // 1,474,560
    float* mpart = W + 26771456;         // 23,040
    float* lpart = W + 26794496;         // 23,040
    float* vmean = W + 33439744;         // 2,048 (aliases xl, post-qkv5)
    float* base  = W + 33441792;         // 2,048
    int*   tidx  = (int*)(W + 33443840); // 1,440 ints

    conv_kernel<<<8961, 256, 0, stream>>>((const float4*)x, (ushort4*)xh, (ushort4*)xl,
                                          Wq, Wk, Wv, WTh, WTl, vmp);
    qkv5_kernel<<<dim3(128, 4), 256, 0, stream>>>(xh, xl, WTh, WTl, Q, K, V, vmp);
    m_kernel<<<32768, 256, 0, stream>>>(Q, K, idx, Mv);
    topk_kernel<<<32, 256, 0, stream>>>(Mv, tidx);
    base_kernel<<<4, 256, 0, stream>>>(vmp, Wo, vmean, base);
    fill_kernel<<<8192, 256, 0, stream>>>((const float4*)base, (float4*)out);
    attn_flash_kernel<<<dim3(FSPLIT, 32), 256, 0, stream>>>(Q, K, V, tidx, Opart, mpart, lpart);
    combine_kernel<<<1440, 256, 0, stream>>>(Opart, mpart, lpart, vmean, Wo, tidx, out);
}